// Round 1
// baseline (230.215 us; speedup 1.0000x reference)
//
#include <hip/hip_runtime.h>

// PixelShuffle1d: x (8, 256, 16384) f32 -> out (8, 64, 65536) f32, upscale=4.
// out[b, c', l*4 + j] = x[b, c'*4 + j, l]
// Flattened with bc = b*64 + c':
//   out[bc*65536 + l*4 + j] = x[bc*65536 + j*16384 + l]
//
// Register 4x4 transpose version:
//   Each thread owns 4 consecutive l positions (one quad-group lg, l0 = lg*4).
//   - 4x global_load_dwordx4: float4 from each source row j (16 B/lane,
//     wave covers 1 KiB contiguous per row per instruction).
//   - in-register transpose (free: just operand naming in the stores).
//   - 4x global_store_dwordx4: 64 B contiguous per thread, wave covers a
//     4 KiB contiguous span -> L2 write-combines the 4 instructions.
// vs previous kernel: 4x fewer load instructions (dword -> dwordx4),
// 4x fewer threads. Both sides now 16 B/lane (float4-copy sweet spot).

constexpr int L = 16384;                 // input inner length
constexpr int QUADS_PER_ROW = L / 4;     // 4096 float4 groups per row
constexpr long TOTAL_THREADS = 8L * 64L * QUADS_PER_ROW;  // 2,097,152

__global__ __launch_bounds__(256) void pixel_shuffle1d_kernel(
    const float* __restrict__ x, float* __restrict__ out) {
    long tid = (long)blockIdx.x * blockDim.x + threadIdx.x;

    int  lg = (int)(tid & (QUADS_PER_ROW - 1));  // quad index within row
    long bc = tid >> 12;                          // b*64 + c'

    // Input: 4 rows, each row j at x[bc*4*L + j*L], take float4 at quad lg.
    const float4* src =
        reinterpret_cast<const float4*>(x + bc * (4L * L)) + lg;
    float4 r0 = src[0 * QUADS_PER_ROW];
    float4 r1 = src[1 * QUADS_PER_ROW];
    float4 r2 = src[2 * QUADS_PER_ROW];
    float4 r3 = src[3 * QUADS_PER_ROW];

    // Output: quad index bc*16384 + l, for l = lg*4 .. lg*4+3 (contiguous).
    float4* dst = reinterpret_cast<float4*>(out) + (bc << 14) + ((long)lg << 2);
    dst[0] = make_float4(r0.x, r1.x, r2.x, r3.x);
    dst[1] = make_float4(r0.y, r1.y, r2.y, r3.y);
    dst[2] = make_float4(r0.z, r1.z, r2.z, r3.z);
    dst[3] = make_float4(r0.w, r1.w, r2.w, r3.w);
}

extern "C" void kernel_launch(void* const* d_in, const int* in_sizes, int n_in,
                              void* d_out, int out_size, void* d_ws, size_t ws_size,
                              hipStream_t stream) {
    const float* x = (const float*)d_in[0];
    float* out = (float*)d_out;

    const int block = 256;
    const long grid = TOTAL_THREADS / block;  // 8192 blocks, exact (no tail)
    pixel_shuffle1d_kernel<<<(int)grid, block, 0, stream>>>(x, out);
}

// Round 2
// 227.139 us; speedup vs baseline: 1.0135x; 1.0135x over previous
//
#include <hip/hip_runtime.h>

// PixelShuffle1d: x (8, 256, 16384) f32 -> out (8, 64, 65536) f32, upscale=4.
// out[b, c', l*4 + j] = x[b, c'*4 + j, l]
// Flattened with bc = b*64 + c':
//   out[bc*65536 + l*4 + j] = x[bc*65536 + j*16384 + l]
//
// LDS-staged transpose so BOTH global sides are fully coalesced:
//   round-0 kernel: coalesced store, scalar (4 B/lane) loads     -> ~79 us
//   round-1 kernel: dwordx4 loads, 64B-strided partial-line stores-> ~79 us
//   this kernel:    dwordx4 contiguous loads AND stores, LDS flip
//
// Block = 256 threads, owns one (bc, 1024-l) tile:
//   load : thread t reads float4 quad t of each of 4 source rows
//          (global_load_dwordx4, wave spans 1 KiB contiguous per row)
//          -> ds_write_b128 into lds[r][t*4] (contiguous, conflict-free)
//   store: thread t emits output quads k = i*256+t as
//          {lds[0][k], lds[1][k], lds[2][k], lds[3][k]}
//          (4x ds_read_b32, lane-consecutive words -> 2 lanes/bank = free)
//          -> global_store_dwordx4, wave spans 1 KiB contiguous.

constexpr int L = 16384;                   // input inner length
constexpr int TILE_L = 1024;               // l-positions per block tile
constexpr int TILES_PER_ROW = L / TILE_L;  // 16
constexpr int BLOCK = 256;
constexpr int QPR = L / 4;                 // float4 quads per input row

__global__ __launch_bounds__(256) void pixel_shuffle1d_kernel(
    const float* __restrict__ x, float* __restrict__ out) {
    __shared__ float lds[4][TILE_L];       // 16 KB

    const int t = threadIdx.x;
    const int tile = blockIdx.x & (TILES_PER_ROW - 1);
    const long bc = blockIdx.x >> 4;       // b*64 + c'
    const int l0 = tile * TILE_L;

    // ---- load phase: 4 rows x 256 quads, all contiguous per instruction
    const float4* src = reinterpret_cast<const float4*>(x + bc * (4L * L) + l0);
#pragma unroll
    for (int r = 0; r < 4; ++r) {
        float4 v = src[r * QPR + t];                       // row r, quad t
        *reinterpret_cast<float4*>(&lds[r][t * 4]) = v;    // ds_write_b128
    }

    __syncthreads();

    // ---- store phase: output quad (bc*16384 + l0 + k) = column k of lds
    float4* dst = reinterpret_cast<float4*>(out) + (bc << 14) + l0;
#pragma unroll
    for (int i = 0; i < 4; ++i) {
        int k = i * BLOCK + t;
        dst[k] = make_float4(lds[0][k], lds[1][k], lds[2][k], lds[3][k]);
    }
}

extern "C" void kernel_launch(void* const* d_in, const int* in_sizes, int n_in,
                              void* d_out, int out_size, void* d_ws, size_t ws_size,
                              hipStream_t stream) {
    const float* x = (const float*)d_in[0];
    float* out = (float*)d_out;

    const int grid = (8 * 64) * TILES_PER_ROW;  // 8192 blocks, no tail
    pixel_shuffle1d_kernel<<<grid, BLOCK, 0, stream>>>(x, out);
}

// Round 4
// 217.738 us; speedup vs baseline: 1.0573x; 1.0432x over previous
//
#include <hip/hip_runtime.h>

// PixelShuffle1d: x (8, 256, 16384) f32 -> out (8, 64, 65536) f32, upscale=4.
// out[b, c', l*4 + j] = x[b, c'*4 + j, l]
// Flattened with bc = b*64 + c':
//   out[bc*65536 + l*4 + j] = x[bc*65536 + j*16384 + l]
//
// Round-2 LDS-staged transpose (both global sides fully coalesced) measured
// ~76 us = 3.5 TB/s effective -- same as the two earlier, differently-shaped
// kernels. Pattern-insensitivity points at memory-system state, not access
// pattern: working set (134 MB in + 134 MB out = 268 MB) exceeds the 256 MB
// Infinity Cache, and streaming writes allocate in L3, thrashing the
// (partially resident, FETCH_SIZE=67MB) input. Round-3/4 lever: NONTEMPORAL
// loads + stores so both streams bypass cache allocation (neither is ever
// re-touched), like the write-only fill kernels that sustain 6.7 TB/s.
//
// Round-3 fix: __builtin_nontemporal_* rejects HIP_vector_type<float,4>*;
// use a clang ext_vector float4 (f32x4) for the global accesses instead.
//
// Structure (unchanged from round 2, verified absmax=0):
//   block = 256 threads, one (bc, 1024-l) tile:
//   load : thread t nt-loads f32x4 quad t of each of 4 source rows
//          (global_load_dwordx4 nt, wave spans 1 KiB contiguous per row)
//          -> ds_write_b128 into lds[r][t*4] (conflict-free)
//   store: thread t emits output quads k = i*256+t as
//          {lds[0][k], lds[1][k], lds[2][k], lds[3][k]}
//          (4x ds_read_b32, 2 lanes/bank = free)
//          -> global_store_dwordx4 nt, wave spans 1 KiB contiguous
//          (16 full 64B lines per instruction -> no RFO).

typedef float f32x4 __attribute__((ext_vector_type(4)));

constexpr int L = 16384;                   // input inner length
constexpr int TILE_L = 1024;               // l-positions per block tile
constexpr int TILES_PER_ROW = L / TILE_L;  // 16
constexpr int BLOCK = 256;
constexpr int QPR = L / 4;                 // float4 quads per input row

__global__ __launch_bounds__(256) void pixel_shuffle1d_kernel(
    const float* __restrict__ x, float* __restrict__ out) {
    __shared__ float lds[4][TILE_L];       // 16 KB

    const int t = threadIdx.x;
    const int tile = blockIdx.x & (TILES_PER_ROW - 1);
    const long bc = blockIdx.x >> 4;       // b*64 + c'
    const int l0 = tile * TILE_L;

    // ---- load phase: 4 rows x 256 quads, contiguous per instruction, nt
    const f32x4* src = reinterpret_cast<const f32x4*>(x + bc * (4L * L) + l0);
#pragma unroll
    for (int r = 0; r < 4; ++r) {
        f32x4 v = __builtin_nontemporal_load(&src[r * QPR + t]);
        *reinterpret_cast<f32x4*>(&lds[r][t * 4]) = v;     // ds_write_b128
    }

    __syncthreads();

    // ---- store phase: output quad (bc*16384 + l0 + k) = column k of lds, nt
    f32x4* dst = reinterpret_cast<f32x4*>(out) + (bc << 14) + l0;
#pragma unroll
    for (int i = 0; i < 4; ++i) {
        int k = i * BLOCK + t;
        f32x4 v = {lds[0][k], lds[1][k], lds[2][k], lds[3][k]};
        __builtin_nontemporal_store(v, &dst[k]);
    }
}

extern "C" void kernel_launch(void* const* d_in, const int* in_sizes, int n_in,
                              void* d_out, int out_size, void* d_ws, size_t ws_size,
                              hipStream_t stream) {
    const float* x = (const float*)d_in[0];
    float* out = (float*)d_out;

    const int grid = (8 * 64) * TILES_PER_ROW;  // 8192 blocks, no tail
    pixel_shuffle1d_kernel<<<grid, BLOCK, 0, stream>>>(x, out);
}